// Round 1
// baseline (296.137 us; speedup 1.0000x reference)
//
#include <hip/hip_runtime.h>

// PointPillarsScatter: out[b][c][y][x] = feat[m][c] where m is the LAST point
// (numpy last-write-wins) with coordinates (b, _, y, x); 0 elsewhere.
// Strategy: winner-index pass (atomicMax on point index) + coalesced gather.

#define NXc 512
#define NYc 512
#define Cc  64

__global__ void __launch_bounds__(256)
winners_kernel(const int* __restrict__ coords, int* __restrict__ winner, int M) {
    int m = blockIdx.x * blockDim.x + threadIdx.x;
    if (m >= M) return;
    // coordinates row: [b, z, y, x] int32, contiguous -> int4 load
    int4 cd = ((const int4*)coords)[m];
    int slot = cd.x * (NYc * NXc) + cd.z * NXc + cd.w;
    atomicMax(&winner[slot], m);   // device-scope by default; last point (max m) wins
}

__global__ void __launch_bounds__(256)
gather_kernel(const float* __restrict__ feat, const int* __restrict__ winner,
              float* __restrict__ out) {
    // One thread per 4 consecutive x of one (b, y). Reads 4 winners once,
    // then loops over channels in groups of 4 with a 4x4 register transpose
    // so every global store is a coalesced float4 (1 KiB per wave).
    int tid = blockIdx.x * blockDim.x + threadIdx.x;   // 0 .. B*NY*NX/4-1
    int x4 = (tid & (NXc / 4 - 1)) * 4;                // 0..508 step 4
    int by = tid >> 7;                                 // NX/4 = 128 -> shift 7
    int y  = by & (NYc - 1);
    int b  = by >> 9;
    const int plane = NYc * NXc;                       // 262144

    int4 w = *(const int4*)(winner + b * plane + y * NXc + x4);

    float* obase = out + (size_t)(b * Cc) * plane + y * NXc + x4;

    #pragma unroll 4
    for (int cg = 0; cg < Cc / 4; ++cg) {
        float4 f0 = {0.f, 0.f, 0.f, 0.f};
        float4 f1 = f0, f2 = f0, f3 = f0;
        if (w.x >= 0) f0 = *(const float4*)(feat + (size_t)w.x * Cc + cg * 4);
        if (w.y >= 0) f1 = *(const float4*)(feat + (size_t)w.y * Cc + cg * 4);
        if (w.z >= 0) f2 = *(const float4*)(feat + (size_t)w.z * Cc + cg * 4);
        if (w.w >= 0) f3 = *(const float4*)(feat + (size_t)w.w * Cc + cg * 4);
        // transpose: channel c+i gets lane-j value feat[m_j][c+i]
        float4 o;
        o = make_float4(f0.x, f1.x, f2.x, f3.x);
        *(float4*)(obase + (size_t)(cg * 4 + 0) * plane) = o;
        o = make_float4(f0.y, f1.y, f2.y, f3.y);
        *(float4*)(obase + (size_t)(cg * 4 + 1) * plane) = o;
        o = make_float4(f0.z, f1.z, f2.z, f3.z);
        *(float4*)(obase + (size_t)(cg * 4 + 2) * plane) = o;
        o = make_float4(f0.w, f1.w, f2.w, f3.w);
        *(float4*)(obase + (size_t)(cg * 4 + 3) * plane) = o;
    }
}

extern "C" void kernel_launch(void* const* d_in, const int* in_sizes, int n_in,
                              void* d_out, int out_size, void* d_ws, size_t ws_size,
                              hipStream_t stream) {
    const float* feat   = (const float*)d_in[0];
    const int*   coords = (const int*)d_in[1];
    float*       out    = (float*)d_out;

    const int M = in_sizes[1] / 4;                 // coordinates is (M,4)
    const int B = out_size / (Cc * NYc * NXc);     // 4

    int* winner = (int*)d_ws;                      // B*NY*NX ints = 4 MiB
    const size_t wbytes = (size_t)B * NYc * NXc * sizeof(int);

    // winner = -1 everywhere (0xFFFFFFFF). ws is re-poisoned each call, so
    // this must run every launch. Memset nodes are graph-capturable.
    hipMemsetAsync(winner, 0xFF, wbytes, stream);

    winners_kernel<<<(M + 255) / 256, 256, 0, stream>>>(coords, winner, M);

    const int nthreads = B * NYc * NXc / 4;        // 262144
    gather_kernel<<<nthreads / 256, 256, 0, stream>>>(feat, winner, out);
}